// Round 12
// baseline (472.899 us; speedup 1.0000x reference)
//
#include <hip/hip_runtime.h>
#include <hip/hip_fp16.h>

// RaBitQ forward: lane-owns-vector quantize (no LDS!) + tail MFMA dequantize.
// x: 262144 vectors of D=128 fp32. P: 128x128 fp32 orthonormal.
// out f32 concat: x_hat[262144*128] | packed[262144*16] | norms16[262144] | x016[262144]
//
// R10 post-mortem: quant was LDS-throughput-bound (~205us of ds_read_b128 on
// the per-CU LDS pipe). Fix: take both operands OFF the LDS pipe.
//   x: per-lane, whole vector in 128 scalar-float VGPRs, each PINNED with
//      asm("+v") on a scalar (R11's float4 pin didn't compile: tied indirect).
//      Prevents R6's rematerialization (VGPR=84, FETCH=2.7GB, 20x x re-read).
//      __launch_bounds__(256,2) -> 256-VGPR budget, 2 waves/SIMD.
//   P: wave-uniform row reads -> SMEM/scalar pipe (SGPR operand into v_fma).
//   Signs/norm/x0/pack: R6 VERBATIM (passed on HW; ascending-d 4-chain).
// Tail dequant per wave (after its x is consumed):
//   masks/scales lane->MFMA-layout via ds_bpermute (no LDS memory needed);
//   A-frag/MFMA/C-D layout R5-proven; B-frags via prep kernel in d_ws (R9).

#define NVEC_TOTAL (4 * 16 * 4096)

typedef short short8 __attribute__((ext_vector_type(8)));
typedef float f32x4 __attribute__((ext_vector_type(4)));
typedef unsigned int u32x4v __attribute__((ext_vector_type(4)));
typedef unsigned long long ull;

__device__ __forceinline__ unsigned short f2bf(float f) {  // fp32 -> bf16 RNE
  unsigned u = __float_as_uint(f);
  return (unsigned short)((u + 0x7FFFu + ((u >> 16) & 1u)) >> 16);
}

__device__ __forceinline__ int bperm(int srclane, int v) {
  return __builtin_amdgcn_ds_bpermute(srclane << 2, v);
}

// ============ prep: build bf16 B-frags (MFMA layout) into d_ws (R9 verbatim) ============
__global__ __launch_bounds__(256, 4) void prep_bfrags(const float* __restrict__ Pm,
                                                      unsigned* __restrict__ ws) {
  const int tid = threadIdx.x;
#pragma unroll
  for (int i = 0; i < 8; ++i) {
    const int s = tid + i * 256;
    const int ks = s >> 9, n = (s >> 6) & 7, l = s & 63;
    const int kb = ks * 32 + (l >> 4) * 8;
    const int f = n * 16 + (l & 15);
    u32x4v wv;
#pragma unroll
    for (int u = 0; u < 4; ++u) {
      const float p0 = Pm[(size_t)(kb + 2 * u) * 128 + f];
      const float p1 = Pm[(size_t)(kb + 2 * u + 1) * 128 + f];
      wv[u] = (unsigned)f2bf(p0) | ((unsigned)f2bf(p1) << 16);
    }
    *(u32x4v*)(ws + s * 4) = wv;
  }
}

// ========================= fused: quantize + tail dequantize =========================
__global__ __launch_bounds__(256, 2) void rabitq_fused(const float* __restrict__ x,
                                                       const float* __restrict__ Pm,
                                                       const unsigned* __restrict__ bw,
                                                       float* __restrict__ out) {
  const int tid = threadIdx.x;
  const int lane = tid & 63;
  const int ww = tid >> 6;
  const int l15 = lane & 15, lg = lane >> 4;
  const int vec = blockIdx.x * 256 + tid;        // my vector (lane-owns-vector)
  const int wbase = blockIdx.x * 256 + ww * 64;  // wave's first vector

  float* const out_pack = out + (size_t)NVEC_TOTAL * 128;
  float* const out_norm = out_pack + (size_t)NVEC_TOTAL * 16;
  float* const out_x0   = out_norm + NVEC_TOTAL;

  // ---- load my x row once into 128 scalar VGPRs, then PIN each scalar ----
  float xr[128];
  {
    const float4* xp = (const float4*)(x + (size_t)vec * 128);
#pragma unroll
    for (int j = 0; j < 32; ++j) {
      const float4 t = xp[j];
      xr[4 * j + 0] = t.x; xr[4 * j + 1] = t.y;
      xr[4 * j + 2] = t.z; xr[4 * j + 3] = t.w;
    }
  }
#pragma unroll
  for (int j = 0; j < 128; ++j) asm volatile("" : "+v"(xr[j]));  // no remat/spill

  ull m01 = 0ull, m23 = 0ull;  // sign bits e=0..63 / 64..127 (LSB = lowest e)
  float s1 = 0.0f, n2 = 0.0f;

#pragma unroll 1
  for (int eg = 0; eg < 32; ++eg) {
    // 4 rotated coords e = eg*4 + q; P rows wave-uniform -> scalar/SMEM pipe
    const float4* p0 = (const float4*)(Pm + (size_t)(eg * 4 + 0) * 128);
    const float4* p1 = (const float4*)(Pm + (size_t)(eg * 4 + 1) * 128);
    const float4* p2 = (const float4*)(Pm + (size_t)(eg * 4 + 2) * 128);
    const float4* p3 = (const float4*)(Pm + (size_t)(eg * 4 + 3) * 128);

    float a0 = 0.f, a1 = 0.f, a2 = 0.f, a3 = 0.f;
#pragma unroll
    for (int j = 0; j < 32; ++j) {
      const float4 q0 = p0[j], q1 = p1[j], q2 = p2[j], q3 = p3[j];
      // ascending-d sequential fmaf chain per e == R6-proven sign chain
      a0 = fmaf(xr[4 * j + 0], q0.x, a0); a0 = fmaf(xr[4 * j + 1], q0.y, a0);
      a0 = fmaf(xr[4 * j + 2], q0.z, a0); a0 = fmaf(xr[4 * j + 3], q0.w, a0);
      a1 = fmaf(xr[4 * j + 0], q1.x, a1); a1 = fmaf(xr[4 * j + 1], q1.y, a1);
      a1 = fmaf(xr[4 * j + 2], q1.z, a1); a1 = fmaf(xr[4 * j + 3], q1.w, a1);
      a2 = fmaf(xr[4 * j + 0], q2.x, a2); a2 = fmaf(xr[4 * j + 1], q2.y, a2);
      a2 = fmaf(xr[4 * j + 2], q2.z, a2); a2 = fmaf(xr[4 * j + 3], q2.w, a2);
      a3 = fmaf(xr[4 * j + 0], q3.x, a3); a3 = fmaf(xr[4 * j + 1], q3.y, a3);
      a3 = fmaf(xr[4 * j + 2], q3.z, a3); a3 = fmaf(xr[4 * j + 3], q3.w, a3);
    }

    const unsigned nib = (a0 >= 0.f ? 1u : 0u) | (a1 >= 0.f ? 2u : 0u) |
                         (a2 >= 0.f ? 4u : 0u) | (a3 >= 0.f ? 8u : 0u);
    if (eg < 16) m01 |= (ull)nib << (eg * 4);
    else         m23 |= (ull)nib << ((eg - 16) * 4);

    s1 += fabsf(a0); s1 += fabsf(a1); s1 += fabsf(a2); s1 += fabsf(a3);
    n2 = fmaf(a0, a0, n2); n2 = fmaf(a1, a1, n2);
    n2 = fmaf(a2, a2, n2); n2 = fmaf(a3, a3, n2);
  }

  // ---- finalize (R6 verbatim) ----
  const float norm = fmaxf(sqrtf(n2), 1e-8f);
  const float n16  = __half2float(__float2half(norm));
  const float x0   = s1 / (128.0f * norm);
  const float x016 = __half2float(__float2half(x0));
  out_norm[vec] = n16;
  out_x0[vec]   = x016;
  const float scale = n16 * x016;

  // ---- packed bytes as floats (R6 verbatim) ----
  {
    float4 f0, f1, f2, f3;
    f0.x = (float)((unsigned)(m01 >>  0) & 255u);
    f0.y = (float)((unsigned)(m01 >>  8) & 255u);
    f0.z = (float)((unsigned)(m01 >> 16) & 255u);
    f0.w = (float)((unsigned)(m01 >> 24) & 255u);
    f1.x = (float)((unsigned)(m01 >> 32) & 255u);
    f1.y = (float)((unsigned)(m01 >> 40) & 255u);
    f1.z = (float)((unsigned)(m01 >> 48) & 255u);
    f1.w = (float)((unsigned)(m01 >> 56) & 255u);
    f2.x = (float)((unsigned)(m23 >>  0) & 255u);
    f2.y = (float)((unsigned)(m23 >>  8) & 255u);
    f2.z = (float)((unsigned)(m23 >> 16) & 255u);
    f2.w = (float)((unsigned)(m23 >> 24) & 255u);
    f3.x = (float)((unsigned)(m23 >> 32) & 255u);
    f3.y = (float)((unsigned)(m23 >> 40) & 255u);
    f3.z = (float)((unsigned)(m23 >> 48) & 255u);
    f3.w = (float)((unsigned)(m23 >> 56) & 255u);
    float4* pp = (float4*)(out_pack + (size_t)vec * 16);
    pp[0] = f0; pp[1] = f1; pp[2] = f2; pp[3] = f3;
  }

  // ================= tail dequant: wave's 64 vecs = 4 MFMA groups =================
  const unsigned w0 = (unsigned)m01, w1 = (unsigned)(m01 >> 32);
  const unsigned w2 = (unsigned)m23, w3 = (unsigned)(m23 >> 32);

#pragma unroll 1
  for (int g = 0; g < 4; ++g) {
    const int gvb = wbase + g * 16;

    // masks of vec (gvb + l15) via cross-lane pull from its owner lane
    const int src = g * 16 + l15;
    unsigned mw[4];
    mw[0] = (unsigned)bperm(src, (int)w0);
    mw[1] = (unsigned)bperm(src, (int)w1);
    mw[2] = (unsigned)bperm(src, (int)w2);
    mw[3] = (unsigned)bperm(src, (int)w3);

    // A-frags : R2/R5-proven construction
    short8 a8[4];
#pragma unroll
    for (int ks = 0; ks < 4; ++ks) {
      const unsigned nb = (~mw[ks]) >> (lg * 8);
      u32x4v ta;
      ta[0] = 0x3F803F80u | ((nb & 1u) << 15)        | ((nb & 2u) << 30);
      ta[1] = 0x3F803F80u | (((nb >> 2) & 1u) << 15) | (((nb >> 2) & 2u) << 30);
      ta[2] = 0x3F803F80u | (((nb >> 4) & 1u) << 15) | (((nb >> 4) & 2u) << 30);
      ta[3] = 0x3F803F80u | (((nb >> 6) & 1u) << 15) | (((nb >> 6) & 2u) << 30);
      a8[ks] = __builtin_bit_cast(short8, ta);
    }

    // D = S @ bf16(P), B-frags from d_ws (L2-hot at tail; R9 read path)
    f32x4 dacc[8];
#pragma unroll
    for (int n = 0; n < 8; ++n) { dacc[n][0] = 0.f; dacc[n][1] = 0.f; dacc[n][2] = 0.f; dacc[n][3] = 0.f; }
#pragma unroll
    for (int n = 0; n < 8; ++n) {
#pragma unroll
      for (int ks = 0; ks < 4; ++ks) {
        const short8 b8 = __builtin_bit_cast(short8, *(const u32x4v*)(bw + (size_t)(ks * 512 + n * 64 + lane) * 4));
        dacc[n] = __builtin_amdgcn_mfma_f32_16x16x32_bf16(a8[ks], b8, dacc[n], 0, 0, 0);
      }
    }

    // scales via cross-lane pull; stores (C/D: col=l15, row=lg*4+reg — proven)
#pragma unroll
    for (int r = 0; r < 4; ++r) {
      const float sc = __int_as_float(bperm(g * 16 + lg * 4 + r, __float_as_int(scale)));
      float* op = out + (size_t)(gvb + lg * 4 + r) * 128 + l15;
#pragma unroll
      for (int n = 0; n < 8; ++n) op[n * 16] = sc * dacc[n][r];
    }
  }
}

extern "C" void kernel_launch(void* const* d_in, const int* in_sizes, int n_in,
                              void* d_out, int out_size, void* d_ws, size_t ws_size,
                              hipStream_t stream) {
  const float* x  = (const float*)d_in[0];
  const float* Pm = (const float*)d_in[1];
  float* out = (float*)d_out;
  // prep: 2048 B-frag slots x 16B = 32 KiB into d_ws.
  hipLaunchKernelGGL(prep_bfrags, dim3(1), dim3(256), 0, stream, Pm, (unsigned*)d_ws);
  // fused: 262144 vec / 256 per block = 1024 blocks; zero LDS.
  hipLaunchKernelGGL(rabitq_fused, dim3(1024), dim3(256), 0, stream,
                     x, Pm, (const unsigned*)d_ws, out);
}

// Round 13
// 308.207 us; speedup vs baseline: 1.5344x; 1.5344x over previous
//
#include <hip/hip_runtime.h>
#include <hip/hip_fp16.h>

// RaBitQ forward, two kernels.
// x: 262144 vectors of D=128 fp32. P: 128x128 fp32 orthonormal.
// out f32 concat: x_hat[262144*128] | packed[262144*16] | norms16[262144] | x016[262144]
//
// Kernel A (quantize): lane = e-row pair (R8-proven numerics), but x is
//   delivered on the VALU pipe via v_readlane from per-lane coalesced VGPRs,
//   NOT via LDS broadcasts (R10/R12 analysis: x-broadcasts = 256 b128/pass
//   >= 164us LDS-pipe floor; P-gathers alone = 64 b128/pass = 41us).
//   Per pass (8 vec): lane (v=lane&7, k=lane>>3) holds x[v][16k..16k+16) in
//   16 VGPRs; x[v][4j+t] = readlane(xq[j&3][t], 8*(j>>2)+v) — SGPR operand
//   into v_fma. Ascending-d fmaf chain == R8 == bit-identical signs.
//   Ballot/reduce/pack: R8 VERBATIM. 512-thr block, 64K LDS P, 2 blocks/CU.
// Kernel B (dequantize): R8 kernel VERBATIM (proven, ~45us).

#define NVEC_TOTAL (4 * 16 * 4096)

typedef short short8 __attribute__((ext_vector_type(8)));
typedef float f32x4 __attribute__((ext_vector_type(4)));
typedef unsigned int u32x4v __attribute__((ext_vector_type(4)));
typedef unsigned long long ull;

__device__ __forceinline__ float rfl_f(float v) {
  return __int_as_float(__builtin_amdgcn_readfirstlane(__float_as_int(v)));
}

__device__ __forceinline__ float rdlane_f(float v, int srclane) {
  return __int_as_float(__builtin_amdgcn_readlane(__float_as_int(v), srclane));
}

__device__ __forceinline__ ull sel8_u64(const ull* a, int s) {
  ull r0 = (s & 1) ? a[1] : a[0];
  ull r1 = (s & 1) ? a[3] : a[2];
  ull r2 = (s & 1) ? a[5] : a[4];
  ull r3 = (s & 1) ? a[7] : a[6];
  ull r4 = (s & 2) ? r1 : r0;
  ull r5 = (s & 2) ? r3 : r2;
  return (s & 4) ? r5 : r4;
}

__device__ __forceinline__ float sel8_f(const float* a, int s) {
  float r0 = (s & 1) ? a[1] : a[0];
  float r1 = (s & 1) ? a[3] : a[2];
  float r2 = (s & 1) ? a[5] : a[4];
  float r3 = (s & 1) ? a[7] : a[6];
  float r4 = (s & 2) ? r1 : r0;
  float r5 = (s & 2) ? r3 : r2;
  return (s & 4) ? r5 : r4;
}

__device__ __forceinline__ unsigned short f2bf(float f) {  // fp32 -> bf16 RNE
  unsigned u = __float_as_uint(f);
  return (unsigned short)((u + 0x7FFFu + ((u >> 16) & 1u)) >> 16);
}

// ========================= Kernel A: quantize =========================
__global__ __launch_bounds__(512, 4) void rabitq_quant(const float* __restrict__ x,
                                                       const float* __restrict__ Pm,
                                                       float* __restrict__ out) {
  __shared__ __align__(16) float Pl[128 * 128];  // 64 KiB swizzled fp32 P

  const int tid = threadIdx.x;
  const int lane = tid & 63;
  const int ww = tid >> 6;

  // ---- stage P into LDS, swizzled (16B blocks, j ^ (row&7)) — R5/R8 stager ----
  {
    const int r = tid >> 2;        // row 0..127, four threads per row
    const int q = tid & 3;
#pragma unroll
    for (int c = 0; c < 8; ++c) {
      const int dd = q * 32 + c * 4;
      const int sj = (((dd >> 2) ^ (r & 7)) << 2);
      const float4 v = *(const float4*)(Pm + (size_t)r * 128 + dd);
      *(float4*)(&Pl[r * 128 + sj]) = v;
    }
  }
  __syncthreads();

  const int w = blockIdx.x * 8 + ww;  // global wave id, 0..8191
  float* const out_pack = out + (size_t)NVEC_TOTAL * 128;
  float* const out_norm = out_pack + (size_t)NVEC_TOTAL * 16;
  float* const out_x0   = out_norm + NVEC_TOTAL;

  const int sw1 = lane & 7;  // row-swizzle key (same for lane and lane+64)

#pragma unroll 1
  for (int t = 0; t < 4; ++t) {
    const int vbase = w * 32 + t * 8;

    // ---- per-lane coalesced x tile: lane (v=lane&7, k=lane>>3) holds
    //      x[vbase+v][16k .. 16k+16) in 4 float4s ----
    float4 xq0, xq1, xq2, xq3;
    {
      const float* xb0 = x + (size_t)(vbase + (lane & 7)) * 128 + (lane >> 3) * 16;
      xq0 = *(const float4*)(xb0 + 0);
      xq1 = *(const float4*)(xb0 + 4);
      xq2 = *(const float4*)(xb0 + 8);
      xq3 = *(const float4*)(xb0 + 12);
    }

    // ---- x_rot = x @ P^T; x via readlane (VALU), P via LDS gathers ----
    float acc_lo[8], acc_hi[8];
#pragma unroll
    for (int v = 0; v < 8; ++v) { acc_lo[v] = 0.f; acc_hi[v] = 0.f; }

#pragma unroll 1
    for (int jo = 0; jo < 8; ++jo) {
      // P chunks for j = 4*jo + ji, ji = 0..3 (swizzled row gathers)
      float4 pl[4], ph[4];
#pragma unroll
      for (int ji = 0; ji < 4; ++ji) {
        const int js = (((4 * jo + ji) ^ sw1) << 2);
        pl[ji] = *(const float4*)(&Pl[lane * 128 + js]);
        ph[ji] = *(const float4*)(&Pl[(lane + 64) * 128 + js]);
      }
      const int lbase = 8 * jo;
#pragma unroll
      for (int v = 0; v < 8; ++v) {
        const int src = lbase + v;   // owner lane of x[v][16*jo ..]
        float al = acc_lo[v], ah = acc_hi[v];
        // ascending-d chain: d = 16*jo + 4*ji + t  (same order as R8)
        {
          const float s0 = rdlane_f(xq0.x, src), s1 = rdlane_f(xq0.y, src);
          const float s2 = rdlane_f(xq0.z, src), s3 = rdlane_f(xq0.w, src);
          al = fmaf(s0, pl[0].x, al); ah = fmaf(s0, ph[0].x, ah);
          al = fmaf(s1, pl[0].y, al); ah = fmaf(s1, ph[0].y, ah);
          al = fmaf(s2, pl[0].z, al); ah = fmaf(s2, ph[0].z, ah);
          al = fmaf(s3, pl[0].w, al); ah = fmaf(s3, ph[0].w, ah);
        }
        {
          const float s0 = rdlane_f(xq1.x, src), s1 = rdlane_f(xq1.y, src);
          const float s2 = rdlane_f(xq1.z, src), s3 = rdlane_f(xq1.w, src);
          al = fmaf(s0, pl[1].x, al); ah = fmaf(s0, ph[1].x, ah);
          al = fmaf(s1, pl[1].y, al); ah = fmaf(s1, ph[1].y, ah);
          al = fmaf(s2, pl[1].z, al); ah = fmaf(s2, ph[1].z, ah);
          al = fmaf(s3, pl[1].w, al); ah = fmaf(s3, ph[1].w, ah);
        }
        {
          const float s0 = rdlane_f(xq2.x, src), s1 = rdlane_f(xq2.y, src);
          const float s2 = rdlane_f(xq2.z, src), s3 = rdlane_f(xq2.w, src);
          al = fmaf(s0, pl[2].x, al); ah = fmaf(s0, ph[2].x, ah);
          al = fmaf(s1, pl[2].y, al); ah = fmaf(s1, ph[2].y, ah);
          al = fmaf(s2, pl[2].z, al); ah = fmaf(s2, ph[2].z, ah);
          al = fmaf(s3, pl[2].w, al); ah = fmaf(s3, ph[2].w, ah);
        }
        {
          const float s0 = rdlane_f(xq3.x, src), s1 = rdlane_f(xq3.y, src);
          const float s2 = rdlane_f(xq3.z, src), s3 = rdlane_f(xq3.w, src);
          al = fmaf(s0, pl[3].x, al); ah = fmaf(s0, ph[3].x, ah);
          al = fmaf(s1, pl[3].y, al); ah = fmaf(s1, ph[3].y, ah);
          al = fmaf(s2, pl[3].z, al); ah = fmaf(s2, ph[3].z, ah);
          al = fmaf(s3, pl[3].w, al); ah = fmaf(s3, ph[3].w, ah);
        }
        acc_lo[v] = al; acc_hi[v] = ah;
      }
    }

    // ---- signs, norm, x0 : R8 VERBATIM ----
    ull bl[8], bh[8];
    float n16v[8], x0v[8];
#pragma unroll
    for (int v = 0; v < 8; ++v) {
      bl[v] = __ballot(acc_lo[v] >= 0.0f);
      bh[v] = __ballot(acc_hi[v] >= 0.0f);
      const float a1 = fabsf(acc_lo[v]);
      const float a2 = fabsf(acc_hi[v]);
      float s1 = a1 + a2;
      float n2 = fmaf(a1, a1, a2 * a2);
#pragma unroll
      for (int off = 32; off > 0; off >>= 1) {
        s1 += __shfl_xor(s1, off);
        n2 += __shfl_xor(n2, off);
      }
      float norm = fmaxf(sqrtf(n2), 1e-8f);
      const float n16  = __half2float(__float2half(norm));
      const float x0   = s1 / (128.0f * norm);
      const float x016 = __half2float(__float2half(x0));
      n16v[v] = rfl_f(n16);
      x0v[v]  = rfl_f(x016);
    }

    // ---- store packed bytes / norms16 / x016 : R8 VERBATIM ----
    {
      const int s = lane & 7;
      const int jb = lane >> 3;
      const ull el = sel8_u64(bl, s);
      const ull eh = sel8_u64(bh, s);
      const float fl = (float)((unsigned)(el >> (8 * jb)) & 255u);
      const float fh = (float)((unsigned)(eh >> (8 * jb)) & 255u);
      out_pack[(size_t)(vbase + s) * 16 + jb] = fl;
      out_pack[(size_t)(vbase + s) * 16 + 8 + jb] = fh;
      if (lane < 16) {
        const float nsel = sel8_f(n16v, s);
        const float xsel = sel8_f(x0v, s);
        if (lane < 8) out_norm[vbase + s] = nsel;
        else          out_x0[vbase + s] = xsel;
      }
    }
  }
}

// ========================= Kernel B: dequantize (R8 VERBATIM) =========================
__global__ __launch_bounds__(256, 4) void rabitq_dequant(const float* __restrict__ Pm,
                                                         float* __restrict__ out) {
  __shared__ __align__(16) unsigned Bp[2048 * 4];  // 32 KiB bf16 B-frags

  const int tid = threadIdx.x, lane = tid & 63, ww = tid >> 6;
  const int l15 = lane & 15, lg = lane >> 4;

#pragma unroll
  for (int i = 0; i < 8; ++i) {
    const int s = tid + i * 256;
    const int ks = s >> 9, n = (s >> 6) & 7, l = s & 63;
    const int kb = ks * 32 + (l >> 4) * 8;
    const int f = n * 16 + (l & 15);
    u32x4v wv;
#pragma unroll
    for (int u = 0; u < 4; ++u) {
      const float p0 = Pm[(size_t)(kb + 2 * u) * 128 + f];
      const float p1 = Pm[(size_t)(kb + 2 * u + 1) * 128 + f];
      wv[u] = (unsigned)f2bf(p0) | ((unsigned)f2bf(p1) << 16);
    }
    *(u32x4v*)(&Bp[s * 4]) = wv;
  }
  __syncthreads();

  const float* const out_pack = out + (size_t)NVEC_TOTAL * 128;
  const float* const out_norm = out_pack + (size_t)NVEC_TOTAL * 16;
  const float* const out_x0   = out_norm + NVEC_TOTAL;

#pragma unroll 1
  for (int t = 0; t < 4; ++t) {
    const int vbase = (blockIdx.x * 4 + ww) * 64 + t * 16;
    const int vec = vbase + l15;

    const float* pb = out_pack + (size_t)vec * 16;
    const float4 b0 = *(const float4*)(pb + 0);
    const float4 b1 = *(const float4*)(pb + 4);
    const float4 b2 = *(const float4*)(pb + 8);
    const float4 b3 = *(const float4*)(pb + 12);
    unsigned mw[4];
    mw[0] = (unsigned)b0.x | ((unsigned)b0.y << 8) | ((unsigned)b0.z << 16) | ((unsigned)b0.w << 24);
    mw[1] = (unsigned)b1.x | ((unsigned)b1.y << 8) | ((unsigned)b1.z << 16) | ((unsigned)b1.w << 24);
    mw[2] = (unsigned)b2.x | ((unsigned)b2.y << 8) | ((unsigned)b2.z << 16) | ((unsigned)b2.w << 24);
    mw[3] = (unsigned)b3.x | ((unsigned)b3.y << 8) | ((unsigned)b3.z << 16) | ((unsigned)b3.w << 24);

    short8 a8[4];
#pragma unroll
    for (int ks = 0; ks < 4; ++ks) {
      const unsigned nb = (~mw[ks]) >> (lg * 8);
      u32x4v ta;
      ta[0] = 0x3F803F80u | ((nb & 1u) << 15)        | ((nb & 2u) << 30);
      ta[1] = 0x3F803F80u | (((nb >> 2) & 1u) << 15) | (((nb >> 2) & 2u) << 30);
      ta[2] = 0x3F803F80u | (((nb >> 4) & 1u) << 15) | (((nb >> 4) & 2u) << 30);
      ta[3] = 0x3F803F80u | (((nb >> 6) & 1u) << 15) | (((nb >> 6) & 2u) << 30);
      a8[ks] = __builtin_bit_cast(short8, ta);
    }

    f32x4 dacc[8];
#pragma unroll
    for (int n = 0; n < 8; ++n) { dacc[n][0] = 0.f; dacc[n][1] = 0.f; dacc[n][2] = 0.f; dacc[n][3] = 0.f; }
#pragma unroll
    for (int n = 0; n < 8; ++n) {
#pragma unroll
      for (int ks = 0; ks < 4; ++ks) {
        const short8 b8 = __builtin_bit_cast(short8, *(const u32x4v*)(&Bp[(ks * 512 + n * 64 + lane) * 4]));
        dacc[n] = __builtin_amdgcn_mfma_f32_16x16x32_bf16(a8[ks], b8, dacc[n], 0, 0, 0);
      }
    }

#pragma unroll
    for (int r = 0; r < 4; ++r) {
      const int row = vbase + lg * 4 + r;
      const float sc = out_norm[row] * out_x0[row];
      float* op = out + (size_t)row * 128 + l15;
#pragma unroll
      for (int n = 0; n < 8; ++n) op[n * 16] = sc * dacc[n][r];
    }
  }
}

extern "C" void kernel_launch(void* const* d_in, const int* in_sizes, int n_in,
                              void* d_out, int out_size, void* d_ws, size_t ws_size,
                              hipStream_t stream) {
  const float* x  = (const float*)d_in[0];
  const float* Pm = (const float*)d_in[1];
  float* out = (float*)d_out;
  // A: 262144 vec / (8 waves * 4 passes * 8 vec) = 1024 blocks, exact cover.
  hipLaunchKernelGGL(rabitq_quant, dim3(1024), dim3(512), 0, stream, x, Pm, out);
  // B: 262144 vec / (4 waves * 4 passes * 16 vec) = 1024 blocks, exact cover.
  hipLaunchKernelGGL(rabitq_dequant, dim3(1024), dim3(256), 0, stream, Pm, out);
}